// Round 3
// baseline (480.561 us; speedup 1.0000x reference)
//
#include <hip/hip_runtime.h>
#include <cstdint>
#include <cstddef>

#define NN 8192
#define FIN 256
#define FOUT 128
#define SLOPE 0.2f
#define SHIFT 8.0f

typedef float f32x4 __attribute__((ext_vector_type(4)));
typedef __bf16 bf16x8 __attribute__((ext_vector_type(8)));
typedef int i32x4 __attribute__((ext_vector_type(4)));
typedef unsigned int u32x4 __attribute__((ext_vector_type(4)));

__device__ __forceinline__ unsigned short f2bf(float f) {
  return __builtin_bit_cast(unsigned short, (__bf16)f);
}

// async global->LDS DMA, 16 B/lane; LDS dest = wave-uniform base + lane*16
__device__ __forceinline__ void async_cp16(void* lds, const void* g) {
  __builtin_amdgcn_global_load_lds(
      (const __attribute__((address_space(1))) void*)g,
      (__attribute__((address_space(3))) void*)lds, 16, 0, 0);
}

// ---------------------------------------------------------------------------
// Kernel A: h = x @ W (fp32 acc) -> ht[FOUT][NN] bf16 (transposed), plus fused
// s-reductions and exp-factor tables + folded zero-init of out/dws. Unchanged.
// ---------------------------------------------------------------------------
__global__ __launch_bounds__(256, 4) void k_hw(const float* __restrict__ x,
                                               const float* __restrict__ W,
                                               const float* __restrict__ a1,
                                               const float* __restrict__ a2,
                                               unsigned short* __restrict__ ht,
                                               float* __restrict__ Etab,
                                               unsigned short* __restrict__ FbfF,
                                               unsigned short* __restrict__ FbfF2,
                                               float* __restrict__ outacc,
                                               float* __restrict__ dws) {
  __shared__ float xs[8][256];
  __shared__ unsigned short tile[128][8];   // [f][row]
  const int tid = threadIdx.x;
  const int rowbase = blockIdx.x * 8;

  {
    f32x4 z = {0.f, 0.f, 0.f, 0.f};
    *(f32x4*)(outacc + (size_t)blockIdx.x * 1024 + tid * 4) = z;
    if (tid < 2) *(f32x4*)(dws + blockIdx.x * 8 + tid * 4) = z;
  }

  #pragma unroll
  for (int it = 0; it < 2; ++it) {
    int fi = it * 1024 + tid * 4;
    int r = fi >> 8, k = fi & 255;
    *(f32x4*)&xs[r][k] = *(const f32x4*)(x + (size_t)(rowbase + r) * FIN + k);
  }
  __syncthreads();

  const int r = tid >> 5;    // 0..7
  const int cg = tid & 31;   // cols cg*4..cg*4+3
  f32x4 acc = {0.f, 0.f, 0.f, 0.f};

  #pragma unroll 8
  for (int k = 0; k < FIN; ++k) {
    f32x4 wv = *(const f32x4*)(W + k * FOUT + cg * 4);
    float xv = xs[r][k];
    acc[0] += xv * wv[0];
    acc[1] += xv * wv[1];
    acc[2] += xv * wv[2];
    acc[3] += xv * wv[3];
  }

  #pragma unroll
  for (int c = 0; c < 4; ++c) tile[cg * 4 + c][r] = f2bf(acc[c]);

  f32x4 av1 = *(const f32x4*)(a1 + cg * 4);
  f32x4 av2 = *(const f32x4*)(a2 + cg * 4);
  float s1 = acc[0] * av1[0] + acc[1] * av1[1] + acc[2] * av1[2] + acc[3] * av1[3];
  float s2 = acc[0] * av2[0] + acc[1] * av2[1] + acc[2] * av2[2] + acc[3] * av2[3];
  #pragma unroll
  for (int off = 16; off > 0; off >>= 1) {
    s1 += __shfl_xor(s1, off, 64);
    s2 += __shfl_xor(s2, off, 64);
  }
  if (cg == 0) {
    const int row = rowbase + r;
    float c0 = s1 + SHIFT;
    float c = fmaxf(c0, SLOPE * c0);
    Etab[(size_t)row * 2]     = __expf(s1 - c);
    Etab[(size_t)row * 2 + 1] = __expf(SLOPE * s1 - c);
    FbfF[row]  = f2bf(__expf(s2));
    FbfF2[row] = f2bf(__expf(SLOPE * s2));
  }
  __syncthreads();

  if (tid < 128) {
    u32x4 v = *(const u32x4*)&tile[tid][0];
    *(u32x4*)(ht + (size_t)tid * NN + rowbase) = v;
  }
}

// ---------------------------------------------------------------------------
// Kernel B: fused masked-softmax aggregation, v11.
// Post-mortem of v10 (164 us, VALUBusy 41%, Occ 39%): ~59% of cycles have ALL
// resident waves co-stalled. Diagnosis: __syncthreads drains vmcnt(0), waiting
// on DMA issued only ONE compute phase (~600 cy) earlier; adj streams from HBM
// (contended latency ~1-2K cy) -> every chunk exposes the tail of that latency
// in every block. Fix = counted-vmcnt protocol (8-phase template, m201/T3+T4):
//  * raw s_barrier pairs: bar(compute c-1 done) -> issue stage -> counted
//    s_waitcnt vmcnt(N) -> bar(chunk c certified) -> compute(c). Never drain
//    the in-flight prefetches.
//  * adj staged 3 CHUNKS AHEAD (sA 4-deep, 16 KB); ht/F depth-2 (L2-resident,
//    1 phase suffices).
//  * F back to LDS DMA (v8 pattern) so the loop's ONLY VMEM = global_load_lds
//    -> exact per-wave vmcnt ledger: wave0 N=4 (ht c+1), wave1 N=5 (+F),
//    waves2,3 N=10 (ht 4 + adj c+1,c+2,c+3). In-order vmcnt retirement (m135)
//    makes the wait a no-op unless a 3-phase-old load is still pending.
//  * tail: clamped source chunk index into the DEAD rotating buffer -> no OOB,
//    uniform issue counts, uniform wait immediates.
//  * LDS 48.5 KB -> 3 blocks/CU: trades 4 waves of occupancy for 3x latency
//    coverage on the adj HBM stream.
// ---------------------------------------------------------------------------
__global__ __launch_bounds__(256, 3) void k_gat(const int* __restrict__ adj,
                                                const unsigned short* __restrict__ ht,
                                                const float* __restrict__ Etab,
                                                const unsigned short* __restrict__ FbfF,
                                                const unsigned short* __restrict__ FbfF2,
                                                float* __restrict__ outacc,
                                                float* __restrict__ dws) {
  __shared__ int sA[4][16 * 64];             // 16 KB : adj, 4-deep, slot s = g^row
  __shared__ unsigned short sH[2][128 * 64]; // 32 KB : ht, 2-deep, slot s = g^(f&7)
  __shared__ unsigned short sF[2][128];      // 512 B : [0,64)=F plane, [64,128)=F2

  const int tid = threadIdx.x;
  const int wave = tid >> 6;
  const int lane = tid & 63;
  const int quad = lane >> 4;
  const int m = lane & 15;                   // A-row / B-col label
  const int rowbase = (int)(blockIdx.x >> 1) * 16;
  const int colbase = (int)(blockIdx.x & 1) * (NN / 2);
  const int row = rowbase + m;

  // ---- runtime layout probes (exact in bf16/fp32) ----
  bf16x8 pm, pinv, pones;
  #pragma unroll
  for (int jj = 0; jj < 8; ++jj) {
    pm[jj] = (__bf16)(float)m;
    pinv[jj] = (__bf16)0.03125f;
    pones[jj] = (__bf16)1.0f;
  }
  f32x4 z = {0.f, 0.f, 0.f, 0.f};
  f32x4 rp = __builtin_amdgcn_mfma_f32_16x16x32_bf16(pm, pinv, z, 0, 0, 0);
  f32x4 cp = __builtin_amdgcn_mfma_f32_16x16x32_bf16(pinv, pm, z, 0, 0, 0);
  int rowmap[4], colmap[4];
  #pragma unroll
  for (int r = 0; r < 4; ++r) {
    rowmap[r] = ((int)(rp[r] + 0.5f)) & 15;
    colmap[r] = ((int)(cp[r] + 0.5f)) & 15;
  }

  const float E  = Etab[(size_t)row * 2];
  const float E2 = Etab[(size_t)row * 2 + 1];
  const int t0 = wave * 2, t1 = wave * 2 + 1;

  f32x4 acc0 = z, acc1 = z, den = z;

  // ---- per-lane DMA source bases (include colbase; chunk idx added per iter)
  const unsigned short* htb[4];
  #pragma unroll
  for (int il = 0; il < 4; ++il) {
    const int i = wave * 4 + il;
    const int f = i * 8 + (lane >> 3);
    const int g = (lane & 7) ^ (lane >> 3);
    htb[il] = ht + (size_t)f * NN + colbase + g * 8;
  }
  const int* adb[2] = {nullptr, nullptr};
  int slotA[2] = {0, 0};
  if (wave >= 2) {
    #pragma unroll
    for (int q2 = 0; q2 < 2; ++q2) {
      const int il = (wave - 2) * 2 + q2;
      const int r = il * 4 + (lane >> 4);
      const int g = (lane & 15) ^ r;
      slotA[q2] = il;
      adb[q2] = adj + (size_t)(rowbase + r) * NN + colbase + g * 4;
    }
  }
  const unsigned short* fbp =
      (lane < 8) ? (FbfF + colbase + lane * 8) : (FbfF2 + colbase + (lane - 8) * 8);

  auto stageH = [&](int buf, int cidx) {
    #pragma unroll
    for (int il = 0; il < 4; ++il)
      async_cp16(&sH[buf][(wave * 4 + il) * 512], htb[il] + cidx * 64);
  };
  auto stageF = [&](int buf, int cidx) {
    if (wave == 1 && lane < 16) async_cp16(&sF[buf][0], fbp + cidx * 64);
  };
  auto stageA = [&](int buf, int cidx) {
    if (wave >= 2) {
      #pragma unroll
      for (int q2 = 0; q2 < 2; ++q2)
        async_cp16(&sA[buf][slotA[q2] * 256], adb[q2] + cidx * 64);
    }
  };

  auto compute = [&](int c) {
    const int bh = c & 1, ba = c & 3;
    #pragma unroll
    for (int k32 = 0; k32 < 2; ++k32) {
      const int g0 = k32 * 8 + quad * 2;
      i32x4 A0 = *(const i32x4*)&sA[ba][m * 64 + ((g0) ^ m) * 4];
      i32x4 A1 = *(const i32x4*)&sA[ba][m * 64 + ((g0 + 1) ^ m) * 4];
      const int jl = k32 * 32 + quad * 8;
      u32x4 Fq = *(const u32x4*)&sF[bh][jl];
      u32x4 Gq = *(const u32x4*)&sF[bh][64 + jl];

      bf16x8 af;
      #pragma unroll
      for (int p = 0; p < 4; ++p) {
        const unsigned fp = Fq[p], gp = Gq[p];
        const float Flo = __builtin_bit_cast(float, fp << 16);
        const float Fhi = __builtin_bit_cast(float, fp & 0xffff0000u);
        const float Glo = __builtin_bit_cast(float, gp << 16);
        const float Ghi = __builtin_bit_cast(float, gp & 0xffff0000u);
        const float wlo = fmaxf(E * Flo, E2 * Glo);
        const float whi = fmaxf(E * Fhi, E2 * Ghi);
        const int avlo = (p < 2) ? A0[p * 2] : A1[p * 2 - 4];
        const int avhi = (p < 2) ? A0[p * 2 + 1] : A1[p * 2 - 3];
        af[p * 2]     = avlo ? (__bf16)wlo : (__bf16)0.0f;
        af[p * 2 + 1] = avhi ? (__bf16)whi : (__bf16)0.0f;
      }

      const int s0 = (k32 * 4 + quad) ^ (m & 7);
      bf16x8 b0 = __builtin_bit_cast(bf16x8,
          *(const u32x4*)&sH[bh][(t0 * 16 + m) * 64 + s0 * 8]);
      bf16x8 b1 = __builtin_bit_cast(bf16x8,
          *(const u32x4*)&sH[bh][(t1 * 16 + m) * 64 + s0 * 8]);

      acc0 = __builtin_amdgcn_mfma_f32_16x16x32_bf16(af, b0, acc0, 0, 0, 0);
      acc1 = __builtin_amdgcn_mfma_f32_16x16x32_bf16(af, b1, acc1, 0, 0, 0);
      den  = __builtin_amdgcn_mfma_f32_16x16x32_bf16(af, pones, den, 0, 0, 0);
    }
  };

  // ---- prologue: ht(0), F(0), adj(0..2) in flight ----
  stageH(0, 0);
  stageF(0, 0);
  stageA(0, 0);
  stageA(1, 1);
  stageA(2, 2);

  #pragma unroll 1
  for (int c = 0; c < 64; ++c) {
    // bar1: all waves finished compute(c-1) -> recycled buffers are free
    __builtin_amdgcn_s_barrier();
    const int cn = (c + 1 < 64) ? c + 1 : 63;   // clamped source; dead buffer at tail
    const int ca = (c + 3 < 64) ? c + 3 : 63;
    stageH((c + 1) & 1, cn);
    stageF((c + 1) & 1, cn);
    stageA((c + 3) & 3, ca);
    // counted wait: chunk c's loads are older than the N just-issued/in-flight
    if (wave >= 2)      asm volatile("s_waitcnt vmcnt(10)" ::: "memory");
    else if (wave == 1) asm volatile("s_waitcnt vmcnt(5)"  ::: "memory");
    else                asm volatile("s_waitcnt vmcnt(4)"  ::: "memory");
    // bar2: every wave certified its chunk-c loads -> LDS chunk c valid
    __builtin_amdgcn_s_barrier();
    __builtin_amdgcn_sched_barrier(0);
    compute(c);
  }

  asm volatile("s_waitcnt vmcnt(0)" ::: "memory");  // drain dead prefetches

  // ---- epilogue: atomic partial accumulation (2 addends/address total) ----
  #pragma unroll
  for (int r = 0; r < 4; ++r) {
    const int orow = rowbase + rowmap[r];
    const int c0 = t0 * 16 + colmap[r];
    const int c1 = t1 * 16 + colmap[r];
    atomicAdd(&outacc[(size_t)orow * FOUT + c0], acc0[r]);
    atomicAdd(&outacc[(size_t)orow * FOUT + c1], acc1[r]);
  }
  if (wave == 0 && m == 0) {
    #pragma unroll
    for (int r = 0; r < 4; ++r) {
      atomicAdd(&dws[rowbase + rowmap[r]], den[r]);
    }
  }
}

// ---------------------------------------------------------------------------
// k_fin: out = num/den + bias
// ---------------------------------------------------------------------------
__global__ __launch_bounds__(256) void k_fin(const float* __restrict__ dws,
                                             const float* __restrict__ bias,
                                             float* __restrict__ out) {
  const int idx = (blockIdx.x * 256 + threadIdx.x) * 4;  // float index
  const int rowi = idx >> 7;
  const int f = idx & 127;
  const float inv = 1.0f / dws[rowi];
  f32x4 v = *(f32x4*)(out + idx);
  f32x4 b = *(const f32x4*)(bias + f);
  v[0] = v[0] * inv + b[0];
  v[1] = v[1] * inv + b[1];
  v[2] = v[2] * inv + b[2];
  v[3] = v[3] * inv + b[3];
  *(f32x4*)(out + idx) = v;
}

// ---------------------------------------------------------------------------
extern "C" void kernel_launch(void* const* d_in, const int* in_sizes, int n_in,
                              void* d_out, int out_size, void* d_ws, size_t ws_size,
                              hipStream_t stream) {
  const float* x    = (const float*)d_in[0];
  const int*   adj  = (const int*)d_in[1];
  const float* W    = (const float*)d_in[2];
  const float* a1   = (const float*)d_in[3];
  const float* a2   = (const float*)d_in[4];
  const float* bias = (const float*)d_in[5];
  float* out = (float*)d_out;

  char* ws = (char*)d_ws;
  unsigned short* ht = (unsigned short*)ws;                            // 2 MB
  float* Etab = (float*)(ws + (size_t)2 * 1024 * 1024);                // 64 KB
  unsigned short* FbfF =
      (unsigned short*)(ws + (size_t)2 * 1024 * 1024 + 64 * 1024);     // 16 KB
  unsigned short* FbfF2 = FbfF + NN;                                   // 16 KB
  float* dws = (float*)(ws + (size_t)2 * 1024 * 1024 + 96 * 1024);     // 32 KB

  k_hw<<<NN / 8, 256, 0, stream>>>(x, W, a1, a2, ht, Etab, FbfF, FbfF2, out, dws);
  k_gat<<<(NN / 16) * 2, 256, 0, stream>>>(adj, ht, Etab, FbfF, FbfF2, out, dws);
  k_fin<<<(NN * FOUT / 4) / 256, 256, 0, stream>>>(dws, bias, out);
}

// Round 4
// 465.047 us; speedup vs baseline: 1.0334x; 1.0334x over previous
//
#include <hip/hip_runtime.h>
#include <cstdint>
#include <cstddef>

#define NN 8192
#define FIN 256
#define FOUT 128
#define SLOPE 0.2f
#define SHIFT 8.0f

typedef float f32x4 __attribute__((ext_vector_type(4)));
typedef __bf16 bf16x8 __attribute__((ext_vector_type(8)));
typedef int i32x4 __attribute__((ext_vector_type(4)));
typedef unsigned int u32x4 __attribute__((ext_vector_type(4)));

__device__ __forceinline__ unsigned short f2bf(float f) {
  return __builtin_bit_cast(unsigned short, (__bf16)f);
}

// async global->LDS DMA; LDS dest = wave-uniform base + lane*size
__device__ __forceinline__ void async_cp16(void* lds, const void* g) {
  __builtin_amdgcn_global_load_lds(
      (const __attribute__((address_space(1))) void*)g,
      (__attribute__((address_space(3))) void*)lds, 16, 0, 0);
}
__device__ __forceinline__ void async_cp4(void* lds, const void* g) {
  __builtin_amdgcn_global_load_lds(
      (const __attribute__((address_space(1))) void*)g,
      (__attribute__((address_space(3))) void*)lds, 4, 0, 0);
}

// ---------------------------------------------------------------------------
// k_pack: adj int32 0/1 -> bitmask, 32x smaller (268 MB -> 8.4 MB).
// This is the ONE unavoidable read of adj, done at streaming speed.
// Word w of row r covers cols 32w..32w+31, bit b = col 32w+b (__ballot order).
// MLP=4 (4 independent 256B loads in flight per wave) to cover HBM latency:
// 32 waves/CU x 4 x 256B = 32 KB in flight/CU > 25 GB/s x 800ns = 20 KB needed.
// ---------------------------------------------------------------------------
__global__ __launch_bounds__(256) void k_pack(const int* __restrict__ adj,
                                              unsigned int* __restrict__ adjp) {
  const int gw = (blockIdx.x * 256 + threadIdx.x) >> 6;  // global wave 0..8191
  const int lane = threadIdx.x & 63;
  // quad-task: 4 consecutive 64-col groups (256 cols). 8192*32 quad-tasks.
  #pragma unroll 1
  for (int qt = gw; qt < 8192 * 32; qt += 8192) {
    const int row = qt >> 5;
    const int j256 = qt & 31;
    const int* p = adj + (size_t)row * NN + j256 * 256 + lane;
    const int a0 = p[0];
    const int a1 = p[64];
    const int a2 = p[128];
    const int a3 = p[192];
    const unsigned long long m0 = __ballot(a0 != 0);
    const unsigned long long m1 = __ballot(a1 != 0);
    const unsigned long long m2 = __ballot(a2 != 0);
    const unsigned long long m3 = __ballot(a3 != 0);
    if (lane == 0) {
      unsigned int* d = adjp + (size_t)row * 256 + j256 * 8;
      u32x4 v0 = {(unsigned)m0, (unsigned)(m0 >> 32), (unsigned)m1, (unsigned)(m1 >> 32)};
      u32x4 v1 = {(unsigned)m2, (unsigned)(m2 >> 32), (unsigned)m3, (unsigned)(m3 >> 32)};
      *(u32x4*)(d) = v0;
      *(u32x4*)(d + 4) = v1;
    }
  }
}

// ---------------------------------------------------------------------------
// Kernel A: h = x @ W (fp32 acc) -> ht[FOUT][NN] bf16 (transposed), fused
// s-reductions + exp tables + zero-init of out/dws. Unchanged from v10.
// ---------------------------------------------------------------------------
__global__ __launch_bounds__(256, 4) void k_hw(const float* __restrict__ x,
                                               const float* __restrict__ W,
                                               const float* __restrict__ a1,
                                               const float* __restrict__ a2,
                                               unsigned short* __restrict__ ht,
                                               float* __restrict__ Etab,
                                               unsigned short* __restrict__ FbfF,
                                               unsigned short* __restrict__ FbfF2,
                                               float* __restrict__ outacc,
                                               float* __restrict__ dws) {
  __shared__ float xs[8][256];
  __shared__ unsigned short tile[128][8];   // [f][row]
  const int tid = threadIdx.x;
  const int rowbase = blockIdx.x * 8;

  {
    f32x4 z = {0.f, 0.f, 0.f, 0.f};
    *(f32x4*)(outacc + (size_t)blockIdx.x * 1024 + tid * 4) = z;
    if (tid < 2) *(f32x4*)(dws + blockIdx.x * 8 + tid * 4) = z;
  }

  #pragma unroll
  for (int it = 0; it < 2; ++it) {
    int fi = it * 1024 + tid * 4;
    int r = fi >> 8, k = fi & 255;
    *(f32x4*)&xs[r][k] = *(const f32x4*)(x + (size_t)(rowbase + r) * FIN + k);
  }
  __syncthreads();

  const int r = tid >> 5;    // 0..7
  const int cg = tid & 31;   // cols cg*4..cg*4+3
  f32x4 acc = {0.f, 0.f, 0.f, 0.f};

  #pragma unroll 8
  for (int k = 0; k < FIN; ++k) {
    f32x4 wv = *(const f32x4*)(W + k * FOUT + cg * 4);
    float xv = xs[r][k];
    acc[0] += xv * wv[0];
    acc[1] += xv * wv[1];
    acc[2] += xv * wv[2];
    acc[3] += xv * wv[3];
  }

  #pragma unroll
  for (int c = 0; c < 4; ++c) tile[cg * 4 + c][r] = f2bf(acc[c]);

  f32x4 av1 = *(const f32x4*)(a1 + cg * 4);
  f32x4 av2 = *(const f32x4*)(a2 + cg * 4);
  float s1 = acc[0] * av1[0] + acc[1] * av1[1] + acc[2] * av1[2] + acc[3] * av1[3];
  float s2 = acc[0] * av2[0] + acc[1] * av2[1] + acc[2] * av2[2] + acc[3] * av2[3];
  #pragma unroll
  for (int off = 16; off > 0; off >>= 1) {
    s1 += __shfl_xor(s1, off, 64);
    s2 += __shfl_xor(s2, off, 64);
  }
  if (cg == 0) {
    const int row = rowbase + r;
    float c0 = s1 + SHIFT;
    float c = fmaxf(c0, SLOPE * c0);
    Etab[(size_t)row * 2]     = __expf(s1 - c);
    Etab[(size_t)row * 2 + 1] = __expf(SLOPE * s1 - c);
    FbfF[row]  = f2bf(__expf(s2));
    FbfF2[row] = f2bf(__expf(SLOPE * s2));
  }
  __syncthreads();

  if (tid < 128) {
    u32x4 v = *(const u32x4*)&tile[tid][0];
    *(u32x4*)(ht + (size_t)tid * NN + rowbase) = v;
  }
}

// ---------------------------------------------------------------------------
// Kernel B: fused masked-softmax aggregation, v12.
// Post-mortem v8-v11: ingest ceiling. DMA bytes/cy/CU pins at ~12-13 across
// schedules (v8 12.0, v10 13.2) = ~8 TB/s chip -> k_gat is BYTES-STAGED-bound.
// v12 cuts bytes 9x per unit work:
//  * adj staged as BITMASK (k_pack): 4 KB -> 128 B per 16rows x 64cols.
//  * 128-row blocks (512 thr, 8 waves; wave owns 16 rows, computes af ONCE
//    for its rows, uses it for ALL 8 output-feature tiles): ht restaged
//    1 GB -> 134 MB total. Grid 64 rowgroups x 8 col-eighths = 512 blocks,
//    2/CU (16 waves/CU).
//  * per-chunk DMA per block: sH 16 KB + sAp 1 KB + sF 256 B for 128x64 adj
//    area (v10: 20.25 KB per 16x64) -> floor ~18 us ingest + ~11 us VALU.
//  * v10's proven barrier/double-buffer protocol (counted-vmcnt gave 0, R3).
//  * epilogue: 8-way atomicAdd partials into out/dws (order-independent sum
//    count per address = 8; fp32 ordering noise ~1e-7 rel, within absmax).
// ---------------------------------------------------------------------------
__global__ __launch_bounds__(512, 4) void k_gat(const unsigned int* __restrict__ adjp,
                                                const unsigned short* __restrict__ ht,
                                                const float* __restrict__ Etab,
                                                const unsigned short* __restrict__ FbfF,
                                                const unsigned short* __restrict__ FbfF2,
                                                float* __restrict__ outacc,
                                                float* __restrict__ dws) {
  __shared__ unsigned short sH[2][128 * 64]; // 32 KB : ht, slot s holds group s^(f&7)
  __shared__ unsigned int sAp[2][2][128];    // 2 KB  : [buf][word(k32)][local row]
  __shared__ unsigned short sF[2][128];      // 512 B : [0,64)=F plane, [64,128)=F2

  const int tid = threadIdx.x;
  const int wave = tid >> 6;                 // 0..7, owns rows 16w..16w+15
  const int lane = tid & 63;
  const int quad = lane >> 4;
  const int m = lane & 15;                   // A-row label within wave's 16
  const int rowbase = (int)(blockIdx.x >> 3) * 128;
  const int colbase = (int)(blockIdx.x & 7) * 1024;
  const int row = rowbase + wave * 16 + m;

  // ---- runtime layout probes (exact in bf16/fp32) ----
  bf16x8 pm, pinv, pones;
  #pragma unroll
  for (int jj = 0; jj < 8; ++jj) {
    pm[jj] = (__bf16)(float)m;
    pinv[jj] = (__bf16)0.03125f;
    pones[jj] = (__bf16)1.0f;
  }
  f32x4 z = {0.f, 0.f, 0.f, 0.f};
  f32x4 rp = __builtin_amdgcn_mfma_f32_16x16x32_bf16(pm, pinv, z, 0, 0, 0);
  f32x4 cp = __builtin_amdgcn_mfma_f32_16x16x32_bf16(pinv, pm, z, 0, 0, 0);
  int rowmap[4], colmap[4];
  #pragma unroll
  for (int r = 0; r < 4; ++r) {
    rowmap[r] = ((int)(rp[r] + 0.5f)) & 15;
    colmap[r] = ((int)(cp[r] + 0.5f)) & 15;
  }

  const float E  = Etab[(size_t)row * 2];
  const float E2 = Etab[(size_t)row * 2 + 1];

  f32x4 acc[8];
  #pragma unroll
  for (int t = 0; t < 8; ++t) acc[t] = z;
  f32x4 den = z;

  // ---- DMA source pointers ----
  // ht: wave stages f-rows 16w..16w+15: instr i = wave*2+il covers f i*8..i*8+7
  const unsigned short* srcH[2];
  #pragma unroll
  for (int il = 0; il < 2; ++il) {
    const int i = wave * 2 + il;
    const int f = i * 8 + (lane >> 3);
    const int g = (lane & 7) ^ (lane >> 3);
    srcH[il] = ht + (size_t)f * NN + colbase + g * 8;
  }
  // adjp: waves 2,3 stage local rows 0..63 / 64..127, words 0,1 (size-4 DMA)
  const unsigned int* srcAp = nullptr;
  if (wave == 2 || wave == 3) {
    const int lr = (wave - 2) * 64 + lane;
    srcAp = adjp + (size_t)(rowbase + lr) * (NN / 32) + (colbase >> 5);
  }
  // F planes: wave 1, lanes 0..15
  const unsigned short* srcF = nullptr;
  if (wave == 1) {
    srcF = (lane < 8) ? (FbfF + colbase + lane * 8)
                      : (FbfF2 + colbase + (lane - 8) * 8);
  }

  auto stage = [&](int b, int c) {
    #pragma unroll
    for (int il = 0; il < 2; ++il)
      async_cp16(&sH[b][(wave * 2 + il) * 512], srcH[il] + c * 64);
    if (wave == 1 && lane < 16) async_cp16(&sF[b][0], srcF + c * 64);
    if (wave == 2 || wave == 3) {
      #pragma unroll
      for (int q = 0; q < 2; ++q)
        async_cp4(&sAp[b][q][(wave - 2) * 64], srcAp + c * 2 + q);
    }
  };

  auto compute = [&](int cs) {
    #pragma unroll
    for (int k32 = 0; k32 < 2; ++k32) {
      const unsigned int word = sAp[cs][k32][wave * 16 + m];
      const unsigned int byt = (word >> (quad * 8)) & 0xffu;
      const int jl = k32 * 32 + quad * 8;
      u32x4 Fq = *(const u32x4*)&sF[cs][jl];        // 8 bf16 F
      u32x4 Gq = *(const u32x4*)&sF[cs][64 + jl];   // 8 bf16 F2

      bf16x8 af;
      #pragma unroll
      for (int p = 0; p < 4; ++p) {
        const unsigned fp = Fq[p], gp = Gq[p];
        const float Flo = __builtin_bit_cast(float, fp << 16);
        const float Fhi = __builtin_bit_cast(float, fp & 0xffff0000u);
        const float Glo = __builtin_bit_cast(float, gp << 16);
        const float Ghi = __builtin_bit_cast(float, gp & 0xffff0000u);
        const float wlo = fmaxf(E * Flo, E2 * Glo);
        const float whi = fmaxf(E * Fhi, E2 * Ghi);
        af[p * 2]     = (byt & (1u << (p * 2)))     ? (__bf16)wlo : (__bf16)0.0f;
        af[p * 2 + 1] = (byt & (1u << (p * 2 + 1))) ? (__bf16)whi : (__bf16)0.0f;
      }

      // ht frags: tile t, slot s = (4k32+quad) ^ (m&7); same af for all 8 t
      const int s0 = (k32 * 4 + quad) ^ (m & 7);
      #pragma unroll
      for (int t = 0; t < 8; ++t) {
        bf16x8 bt = __builtin_bit_cast(bf16x8,
            *(const u32x4*)&sH[cs][(t * 16 + m) * 64 + s0 * 8]);
        acc[t] = __builtin_amdgcn_mfma_f32_16x16x32_bf16(af, bt, acc[t], 0, 0, 0);
      }
      den = __builtin_amdgcn_mfma_f32_16x16x32_bf16(af, pones, den, 0, 0, 0);
    }
  };

  stage(0, 0);   // chunk 0 -> buffer 0

  // 16 chunks of 64 cols over this block's 1024-col eighth; v10 protocol:
  // barrier drains chunk c's DMA (issued one compute phase ago), then prefetch.
  #pragma unroll 1
  for (int c = 0; c < 16; c += 2) {
    __syncthreads();                 // drains chunk c DMA; fences buf1 readers
    stage(1, c + 1);                 // prefetch c+1: in flight across compute
    compute(0);                      // chunk c (buffer 0)
    __syncthreads();                 // drains chunk c+1; fences buf0 readers
    if (c + 2 < 16) stage(0, c + 2); // prefetch c+2
    compute(1);                      // chunk c+1 (buffer 1)
  }

  // ---- epilogue: 8-way atomic partial accumulation (one per col-eighth) ----
  #pragma unroll
  for (int r = 0; r < 4; ++r) {
    const int orow = rowbase + wave * 16 + rowmap[r];
    #pragma unroll
    for (int t = 0; t < 8; ++t) {
      atomicAdd(&outacc[(size_t)orow * FOUT + t * 16 + colmap[r]], acc[t][r]);
    }
  }
  // den: all 16 m-lanes hold identical copies; add once per row.
  if (m == 0) {
    #pragma unroll
    for (int r = 0; r < 4; ++r) {
      atomicAdd(&dws[rowbase + wave * 16 + rowmap[r]], den[r]);
    }
  }
}

// ---------------------------------------------------------------------------
// k_fin: out = num/den + bias
// ---------------------------------------------------------------------------
__global__ __launch_bounds__(256) void k_fin(const float* __restrict__ dws,
                                             const float* __restrict__ bias,
                                             float* __restrict__ out) {
  const int idx = (blockIdx.x * 256 + threadIdx.x) * 4;  // float index
  const int rowi = idx >> 7;
  const int f = idx & 127;
  const float inv = 1.0f / dws[rowi];
  f32x4 v = *(f32x4*)(out + idx);
  f32x4 b = *(const f32x4*)(bias + f);
  v[0] = v[0] * inv + b[0];
  v[1] = v[1] * inv + b[1];
  v[2] = v[2] * inv + b[2];
  v[3] = v[3] * inv + b[3];
  *(f32x4*)(out + idx) = v;
}

// ---------------------------------------------------------------------------
extern "C" void kernel_launch(void* const* d_in, const int* in_sizes, int n_in,
                              void* d_out, int out_size, void* d_ws, size_t ws_size,
                              hipStream_t stream) {
  const float* x    = (const float*)d_in[0];
  const int*   adj  = (const int*)d_in[1];
  const float* W    = (const float*)d_in[2];
  const float* a1   = (const float*)d_in[3];
  const float* a2   = (const float*)d_in[4];
  const float* bias = (const float*)d_in[5];
  float* out = (float*)d_out;

  char* ws = (char*)d_ws;
  unsigned short* ht = (unsigned short*)ws;                            // 2 MB
  float* Etab = (float*)(ws + (size_t)2 * 1024 * 1024);                // 64 KB
  unsigned short* FbfF =
      (unsigned short*)(ws + (size_t)2 * 1024 * 1024 + 64 * 1024);     // 16 KB
  unsigned short* FbfF2 = FbfF + NN;                                   // 16 KB
  float* dws = (float*)(ws + (size_t)2 * 1024 * 1024 + 96 * 1024);     // 32 KB
  unsigned int* adjp =
      (unsigned int*)(ws + (size_t)2 * 1024 * 1024 + 128 * 1024);      // 8 MB

  k_pack<<<2048, 256, 0, stream>>>(adj, adjp);
  k_hw<<<NN / 8, 256, 0, stream>>>(x, W, a1, a2, ht, Etab, FbfF, FbfF2, out, dws);
  k_gat<<<512, 512, 0, stream>>>(adjp, ht, Etab, FbfF, FbfF2, out, dws);
  k_fin<<<(NN * FOUT / 4) / 256, 256, 0, stream>>>(dws, bias, out);
}

// Round 5
// 454.371 us; speedup vs baseline: 1.0576x; 1.0235x over previous
//
#include <hip/hip_runtime.h>
#include <cstdint>
#include <cstddef>

#define NN 8192
#define FIN 256
#define FOUT 128
#define SLOPE 0.2f
#define SHIFT 8.0f

typedef float f32x4 __attribute__((ext_vector_type(4)));
typedef __bf16 bf16x8 __attribute__((ext_vector_type(8)));
typedef int i32x4 __attribute__((ext_vector_type(4)));
typedef unsigned int u32x4 __attribute__((ext_vector_type(4)));

__device__ __forceinline__ unsigned short f2bf(float f) {
  return __builtin_bit_cast(unsigned short, (__bf16)f);
}

// async global->LDS DMA; LDS dest = wave-uniform base + lane*16; per-lane src
__device__ __forceinline__ void async_cp16(void* lds, const void* g) {
  __builtin_amdgcn_global_load_lds(
      (const __attribute__((address_space(1))) void*)g,
      (__attribute__((address_space(3))) void*)lds, 16, 0, 0);
}

// ---------------------------------------------------------------------------
// k_pack v2: adj int32 0/1 -> bitmask, CHUNK-CONTIGUOUS layout for k_gat.
// v12 post-mortem: row-major adjp forced k_gat to stage it with 4-byte DMA at
// 1 KB lane stride = 64 cache lines per instr for 256 B (TA scatter, the v9
// disease). New layout: for k_gat block (RB,CB) and chunk c (64 cols), the
// 256 mask words (w=0,1 x 128 rows) are CONTIGUOUS:
//   adjp2[((RB*8+CB)*16 + c)*256 + w*128 + r]
//     = bits for row RB*128+r, cols CB*1024 + c*64 + w*32  (bit b = col+b).
// Reads stay fully coalesced (256 B/row-segment per lane-group); stores are
// an 8-lane 4 B scatter per task: 8.4 MB scattered vs 268 MB coalesced reads.
// ---------------------------------------------------------------------------
__global__ __launch_bounds__(256) void k_pack(const int* __restrict__ adj,
                                              unsigned int* __restrict__ adjp2) {
  const int gw = (blockIdx.x * 256 + threadIdx.x) >> 6;  // global wave 0..8191
  const int lane = threadIdx.x & 63;
  #pragma unroll 1
  for (int qt = gw; qt < 8192 * 32; qt += 8192) {
    const int row = qt >> 5;
    const int j256 = qt & 31;          // covers cols j256*256 .. +255
    const int* p = adj + (size_t)row * NN + j256 * 256 + lane;
    const int a0 = p[0];
    const int a1 = p[64];
    const int a2 = p[128];
    const int a3 = p[192];
    const unsigned long long m0 = __ballot(a0 != 0);
    const unsigned long long m1 = __ballot(a1 != 0);
    const unsigned long long m2 = __ballot(a2 != 0);
    const unsigned long long m3 = __ballot(a3 != 0);
    if (lane < 8) {
      // lane k stores global word j256*8+k (ballot results are wave-uniform)
      const int wg = j256 * 8 + lane;
      const int CB = wg >> 5, ch = (wg >> 1) & 15, w = wg & 1;
      const int RB = row >> 7, r = row & 127;
      const int sel = lane >> 1;
      const unsigned long long mk =
          (sel == 0) ? m0 : (sel == 1) ? m1 : (sel == 2) ? m2 : m3;
      const unsigned int val = (lane & 1) ? (unsigned)(mk >> 32) : (unsigned)mk;
      adjp2[(((size_t)RB * 8 + CB) * 16 + ch) * 256 + w * 128 + r] = val;
    }
  }
}

// ---------------------------------------------------------------------------
// Kernel A: h = x @ W (fp32 acc) -> ht[FOUT][NN] bf16 (transposed), fused
// s-reductions + exp tables + zero-init of out/dws. Unchanged.
// ---------------------------------------------------------------------------
__global__ __launch_bounds__(256, 4) void k_hw(const float* __restrict__ x,
                                               const float* __restrict__ W,
                                               const float* __restrict__ a1,
                                               const float* __restrict__ a2,
                                               unsigned short* __restrict__ ht,
                                               float* __restrict__ Etab,
                                               unsigned short* __restrict__ FbfF,
                                               unsigned short* __restrict__ FbfF2,
                                               float* __restrict__ outacc,
                                               float* __restrict__ dws) {
  __shared__ float xs[8][256];
  __shared__ unsigned short tile[128][8];   // [f][row]
  const int tid = threadIdx.x;
  const int rowbase = blockIdx.x * 8;

  {
    f32x4 z = {0.f, 0.f, 0.f, 0.f};
    *(f32x4*)(outacc + (size_t)blockIdx.x * 1024 + tid * 4) = z;
    if (tid < 2) *(f32x4*)(dws + blockIdx.x * 8 + tid * 4) = z;
  }

  #pragma unroll
  for (int it = 0; it < 2; ++it) {
    int fi = it * 1024 + tid * 4;
    int r = fi >> 8, k = fi & 255;
    *(f32x4*)&xs[r][k] = *(const f32x4*)(x + (size_t)(rowbase + r) * FIN + k);
  }
  __syncthreads();

  const int r = tid >> 5;    // 0..7
  const int cg = tid & 31;   // cols cg*4..cg*4+3
  f32x4 acc = {0.f, 0.f, 0.f, 0.f};

  #pragma unroll 8
  for (int k = 0; k < FIN; ++k) {
    f32x4 wv = *(const f32x4*)(W + k * FOUT + cg * 4);
    float xv = xs[r][k];
    acc[0] += xv * wv[0];
    acc[1] += xv * wv[1];
    acc[2] += xv * wv[2];
    acc[3] += xv * wv[3];
  }

  #pragma unroll
  for (int c = 0; c < 4; ++c) tile[cg * 4 + c][r] = f2bf(acc[c]);

  f32x4 av1 = *(const f32x4*)(a1 + cg * 4);
  f32x4 av2 = *(const f32x4*)(a2 + cg * 4);
  float s1 = acc[0] * av1[0] + acc[1] * av1[1] + acc[2] * av1[2] + acc[3] * av1[3];
  float s2 = acc[0] * av2[0] + acc[1] * av2[1] + acc[2] * av2[2] + acc[3] * av2[3];
  #pragma unroll
  for (int off = 16; off > 0; off >>= 1) {
    s1 += __shfl_xor(s1, off, 64);
    s2 += __shfl_xor(s2, off, 64);
  }
  if (cg == 0) {
    const int row = rowbase + r;
    float c0 = s1 + SHIFT;
    float c = fmaxf(c0, SLOPE * c0);
    Etab[(size_t)row * 2]     = __expf(s1 - c);
    Etab[(size_t)row * 2 + 1] = __expf(SLOPE * s1 - c);
    FbfF[row]  = f2bf(__expf(s2));
    FbfF2[row] = f2bf(__expf(SLOPE * s2));
  }
  __syncthreads();

  if (tid < 128) {
    u32x4 v = *(const u32x4*)&tile[tid][0];
    *(u32x4*)(ht + (size_t)tid * NN + rowbase) = v;
  }
}

// ---------------------------------------------------------------------------
// Kernel B: fused masked-softmax aggregation, v13.
// v12 post-mortem (k_gat ~124 us inferred vs ~25 modeled): adjp staged with
// async_cp4 at 1 KB lane stride = 64 lines per DMA instr; per chunk 256 line
// gathers for 1 KB, exposed at every barrier drain with only 2 blocks/CU.
// v13: adjp2 is chunk-contiguous (see k_pack), staged with ONE coalesced
// cp16 by wave 2 (16 lines / 1 KB -> same efficiency as sH). Everything
// else (128-row blocks, 8 output tiles per wave, bitmask af, v10 barrier
// protocol, 8-way atomic finish) unchanged from v12.
// ---------------------------------------------------------------------------
__global__ __launch_bounds__(512, 4) void k_gat(const unsigned int* __restrict__ adjp2,
                                                const unsigned short* __restrict__ ht,
                                                const float* __restrict__ Etab,
                                                const unsigned short* __restrict__ FbfF,
                                                const unsigned short* __restrict__ FbfF2,
                                                float* __restrict__ outacc,
                                                float* __restrict__ dws) {
  __shared__ unsigned short sH[2][128 * 64]; // 32 KB : ht, slot s holds group s^(f&7)
  __shared__ unsigned int sAp[2][2][128];    // 2 KB  : [buf][word(k32)][local row]
  __shared__ unsigned short sF[2][128];      // 512 B : [0,64)=F plane, [64,128)=F2

  const int tid = threadIdx.x;
  const int wave = tid >> 6;                 // 0..7, owns rows 16w..16w+15
  const int lane = tid & 63;
  const int quad = lane >> 4;
  const int m = lane & 15;                   // A-row label within wave's 16
  const int rowbase = (int)(blockIdx.x >> 3) * 128;
  const int colbase = (int)(blockIdx.x & 7) * 1024;
  const int row = rowbase + wave * 16 + m;

  // ---- runtime layout probes (exact in bf16/fp32) ----
  bf16x8 pm, pinv, pones;
  #pragma unroll
  for (int jj = 0; jj < 8; ++jj) {
    pm[jj] = (__bf16)(float)m;
    pinv[jj] = (__bf16)0.03125f;
    pones[jj] = (__bf16)1.0f;
  }
  f32x4 z = {0.f, 0.f, 0.f, 0.f};
  f32x4 rp = __builtin_amdgcn_mfma_f32_16x16x32_bf16(pm, pinv, z, 0, 0, 0);
  f32x4 cp = __builtin_amdgcn_mfma_f32_16x16x32_bf16(pinv, pm, z, 0, 0, 0);
  int rowmap[4], colmap[4];
  #pragma unroll
  for (int r = 0; r < 4; ++r) {
    rowmap[r] = ((int)(rp[r] + 0.5f)) & 15;
    colmap[r] = ((int)(cp[r] + 0.5f)) & 15;
  }

  const float E  = Etab[(size_t)row * 2];
  const float E2 = Etab[(size_t)row * 2 + 1];

  f32x4 acc[8];
  #pragma unroll
  for (int t = 0; t < 8; ++t) acc[t] = z;
  f32x4 den = z;

  // ---- DMA source pointers ----
  // ht: wave stages f-rows 16w..16w+15: instr i = wave*2+il covers f i*8..i*8+7
  const unsigned short* srcH[2];
  #pragma unroll
  for (int il = 0; il < 2; ++il) {
    const int i = wave * 2 + il;
    const int f = i * 8 + (lane >> 3);
    const int g = (lane & 7) ^ (lane >> 3);
    srcH[il] = ht + (size_t)f * NN + colbase + g * 8;
  }
  // adjp2: chunk-contiguous 1 KB blocks; block-linear index == blockIdx.x
  const unsigned int* srcAp = adjp2 + (size_t)blockIdx.x * 4096 + lane * 4;
  // F planes: wave 1, lanes 0..15
  const unsigned short* srcF = nullptr;
  if (wave == 1) {
    srcF = (lane < 8) ? (FbfF + colbase + lane * 8)
                      : (FbfF2 + colbase + (lane - 8) * 8);
  }

  auto stage = [&](int b, int c) {
    #pragma unroll
    for (int il = 0; il < 2; ++il)
      async_cp16(&sH[b][(wave * 2 + il) * 512], srcH[il] + c * 64);
    if (wave == 1 && lane < 16) async_cp16(&sF[b][0], srcF + c * 64);
    if (wave == 2) async_cp16(&sAp[b][0][0], srcAp + c * 256);
  };

  auto compute = [&](int cs) {
    #pragma unroll
    for (int k32 = 0; k32 < 2; ++k32) {
      const unsigned int word = sAp[cs][k32][wave * 16 + m];
      const unsigned int byt = (word >> (quad * 8)) & 0xffu;
      const int jl = k32 * 32 + quad * 8;
      u32x4 Fq = *(const u32x4*)&sF[cs][jl];        // 8 bf16 F
      u32x4 Gq = *(const u32x4*)&sF[cs][64 + jl];   // 8 bf16 F2

      bf16x8 af;
      #pragma unroll
      for (int p = 0; p < 4; ++p) {
        const unsigned fp = Fq[p], gp = Gq[p];
        const float Flo = __builtin_bit_cast(float, fp << 16);
        const float Fhi = __builtin_bit_cast(float, fp & 0xffff0000u);
        const float Glo = __builtin_bit_cast(float, gp << 16);
        const float Ghi = __builtin_bit_cast(float, gp & 0xffff0000u);
        const float wlo = fmaxf(E * Flo, E2 * Glo);
        const float whi = fmaxf(E * Fhi, E2 * Ghi);
        af[p * 2]     = (byt & (1u << (p * 2)))     ? (__bf16)wlo : (__bf16)0.0f;
        af[p * 2 + 1] = (byt & (1u << (p * 2 + 1))) ? (__bf16)whi : (__bf16)0.0f;
      }

      // ht frags: tile t, slot s = (4k32+quad) ^ (m&7); same af for all 8 t
      const int s0 = (k32 * 4 + quad) ^ (m & 7);
      #pragma unroll
      for (int t = 0; t < 8; ++t) {
        bf16x8 bt = __builtin_bit_cast(bf16x8,
            *(const u32x4*)&sH[cs][(t * 16 + m) * 64 + s0 * 8]);
        acc[t] = __builtin_amdgcn_mfma_f32_16x16x32_bf16(af, bt, acc[t], 0, 0, 0);
      }
      den = __builtin_amdgcn_mfma_f32_16x16x32_bf16(af, pones, den, 0, 0, 0);
    }
  };

  stage(0, 0);   // chunk 0 -> buffer 0

  // 16 chunks of 64 cols over this block's 1024-col eighth; v10 protocol:
  // barrier drains chunk c's DMA (issued one compute phase ago), then prefetch.
  #pragma unroll 1
  for (int c = 0; c < 16; c += 2) {
    __syncthreads();                 // drains chunk c DMA; fences buf1 readers
    stage(1, c + 1);                 // prefetch c+1: in flight across compute
    compute(0);                      // chunk c (buffer 0)
    __syncthreads();                 // drains chunk c+1; fences buf0 readers
    if (c + 2 < 16) stage(0, c + 2); // prefetch c+2
    compute(1);                      // chunk c+1 (buffer 1)
  }

  // ---- epilogue: 8-way atomic partial accumulation (one per col-eighth) ----
  #pragma unroll
  for (int r = 0; r < 4; ++r) {
    const int orow = rowbase + wave * 16 + rowmap[r];
    #pragma unroll
    for (int t = 0; t < 8; ++t) {
      atomicAdd(&outacc[(size_t)orow * FOUT + t * 16 + colmap[r]], acc[t][r]);
    }
  }
  // den: all 16 m-lanes hold identical copies; add once per row.
  if (m == 0) {
    #pragma unroll
    for (int r = 0; r < 4; ++r) {
      atomicAdd(&dws[rowbase + wave * 16 + rowmap[r]], den[r]);
    }
  }
}

// ---------------------------------------------------------------------------
// k_fin: out = num/den + bias
// ---------------------------------------------------------------------------
__global__ __launch_bounds__(256) void k_fin(const float* __restrict__ dws,
                                             const float* __restrict__ bias,
                                             float* __restrict__ out) {
  const int idx = (blockIdx.x * 256 + threadIdx.x) * 4;  // float index
  const int rowi = idx >> 7;
  const int f = idx & 127;
  const float inv = 1.0f / dws[rowi];
  f32x4 v = *(f32x4*)(out + idx);
  f32x4 b = *(const f32x4*)(bias + f);
  v[0] = v[0] * inv + b[0];
  v[1] = v[1] * inv + b[1];
  v[2] = v[2] * inv + b[2];
  v[3] = v[3] * inv + b[3];
  *(f32x4*)(out + idx) = v;
}

// ---------------------------------------------------------------------------
extern "C" void kernel_launch(void* const* d_in, const int* in_sizes, int n_in,
                              void* d_out, int out_size, void* d_ws, size_t ws_size,
                              hipStream_t stream) {
  const float* x    = (const float*)d_in[0];
  const int*   adj  = (const int*)d_in[1];
  const float* W    = (const float*)d_in[2];
  const float* a1   = (const float*)d_in[3];
  const float* a2   = (const float*)d_in[4];
  const float* bias = (const float*)d_in[5];
  float* out = (float*)d_out;

  char* ws = (char*)d_ws;
  unsigned short* ht = (unsigned short*)ws;                            // 2 MB
  float* Etab = (float*)(ws + (size_t)2 * 1024 * 1024);                // 64 KB
  unsigned short* FbfF =
      (unsigned short*)(ws + (size_t)2 * 1024 * 1024 + 64 * 1024);     // 16 KB
  unsigned short* FbfF2 = FbfF + NN;                                   // 16 KB
  float* dws = (float*)(ws + (size_t)2 * 1024 * 1024 + 96 * 1024);     // 32 KB
  unsigned int* adjp2 =
      (unsigned int*)(ws + (size_t)2 * 1024 * 1024 + 128 * 1024);      // 8 MB

  k_pack<<<2048, 256, 0, stream>>>(adj, adjp2);
  k_hw<<<NN / 8, 256, 0, stream>>>(x, W, a1, a2, ht, Etab, FbfF, FbfF2, out, dws);
  k_gat<<<512, 512, 0, stream>>>(adjp2, ht, Etab, FbfF, FbfF2, out, dws);
  k_fin<<<(NN * FOUT / 4) / 256, 256, 0, stream>>>(dws, bias, out);
}

// Round 6
// 442.111 us; speedup vs baseline: 1.0870x; 1.0277x over previous
//
#include <hip/hip_runtime.h>
#include <cstdint>
#include <cstddef>

#define NN 8192
#define FIN 256
#define FOUT 128
#define SLOPE 0.2f
#define SHIFT 8.0f

typedef float f32x4 __attribute__((ext_vector_type(4)));
typedef __bf16 bf16x8 __attribute__((ext_vector_type(8)));
typedef int i32x4 __attribute__((ext_vector_type(4)));
typedef unsigned int u32x4 __attribute__((ext_vector_type(4)));

__device__ __forceinline__ unsigned short f2bf(float f) {
  return __builtin_bit_cast(unsigned short, (__bf16)f);
}

// async global->LDS DMA; LDS dest = wave-uniform base + lane*16; per-lane src
__device__ __forceinline__ void async_cp16(void* lds, const void* g) {
  __builtin_amdgcn_global_load_lds(
      (const __attribute__((address_space(1))) void*)g,
      (__attribute__((address_space(3))) void*)lds, 16, 0, 0);
}

// ---------------------------------------------------------------------------
// k_pack: adj int32 0/1 -> bitmask, chunk-contiguous layout (unchanged v13).
//   adjp2[((RB*8+CB)*16 + c)*256 + w*128 + r]
//     = bits for row RB*128+r, cols CB*1024 + c*64 + w*32  (bit b = col+b).
// ---------------------------------------------------------------------------
__global__ __launch_bounds__(256) void k_pack(const int* __restrict__ adj,
                                              unsigned int* __restrict__ adjp2) {
  const int gw = (blockIdx.x * 256 + threadIdx.x) >> 6;  // global wave 0..8191
  const int lane = threadIdx.x & 63;
  #pragma unroll 1
  for (int qt = gw; qt < 8192 * 32; qt += 8192) {
    const int row = qt >> 5;
    const int j256 = qt & 31;          // covers cols j256*256 .. +255
    const int* p = adj + (size_t)row * NN + j256 * 256 + lane;
    const int a0 = p[0];
    const int a1 = p[64];
    const int a2 = p[128];
    const int a3 = p[192];
    const unsigned long long m0 = __ballot(a0 != 0);
    const unsigned long long m1 = __ballot(a1 != 0);
    const unsigned long long m2 = __ballot(a2 != 0);
    const unsigned long long m3 = __ballot(a3 != 0);
    if (lane < 8) {
      const int wg = j256 * 8 + lane;
      const int CB = wg >> 5, ch = (wg >> 1) & 15, w = wg & 1;
      const int RB = row >> 7, r = row & 127;
      const int sel = lane >> 1;
      const unsigned long long mk =
          (sel == 0) ? m0 : (sel == 1) ? m1 : (sel == 2) ? m2 : m3;
      const unsigned int val = (lane & 1) ? (unsigned)(mk >> 32) : (unsigned)mk;
      adjp2[(((size_t)RB * 8 + CB) * 16 + ch) * 256 + w * 128 + r] = val;
    }
  }
}

// ---------------------------------------------------------------------------
// Kernel A: h = x @ W (fp32 acc) -> ht[FOUT][NN] bf16 (transposed), fused
// s-reductions + exp tables. v14: zero-init removed (no atomics anywhere;
// part/denp are fully overwritten by k_gat, out by k_fin).
// ---------------------------------------------------------------------------
__global__ __launch_bounds__(256, 4) void k_hw(const float* __restrict__ x,
                                               const float* __restrict__ W,
                                               const float* __restrict__ a1,
                                               const float* __restrict__ a2,
                                               unsigned short* __restrict__ ht,
                                               float* __restrict__ Etab,
                                               unsigned short* __restrict__ FbfF,
                                               unsigned short* __restrict__ FbfF2) {
  __shared__ float xs[8][256];
  __shared__ unsigned short tile[128][8];   // [f][row]
  const int tid = threadIdx.x;
  const int rowbase = blockIdx.x * 8;

  #pragma unroll
  for (int it = 0; it < 2; ++it) {
    int fi = it * 1024 + tid * 4;
    int r = fi >> 8, k = fi & 255;
    *(f32x4*)&xs[r][k] = *(const f32x4*)(x + (size_t)(rowbase + r) * FIN + k);
  }
  __syncthreads();

  const int r = tid >> 5;    // 0..7
  const int cg = tid & 31;   // cols cg*4..cg*4+3
  f32x4 acc = {0.f, 0.f, 0.f, 0.f};

  #pragma unroll 8
  for (int k = 0; k < FIN; ++k) {
    f32x4 wv = *(const f32x4*)(W + k * FOUT + cg * 4);
    float xv = xs[r][k];
    acc[0] += xv * wv[0];
    acc[1] += xv * wv[1];
    acc[2] += xv * wv[2];
    acc[3] += xv * wv[3];
  }

  #pragma unroll
  for (int c = 0; c < 4; ++c) tile[cg * 4 + c][r] = f2bf(acc[c]);

  f32x4 av1 = *(const f32x4*)(a1 + cg * 4);
  f32x4 av2 = *(const f32x4*)(a2 + cg * 4);
  float s1 = acc[0] * av1[0] + acc[1] * av1[1] + acc[2] * av1[2] + acc[3] * av1[3];
  float s2 = acc[0] * av2[0] + acc[1] * av2[1] + acc[2] * av2[2] + acc[3] * av2[3];
  #pragma unroll
  for (int off = 16; off > 0; off >>= 1) {
    s1 += __shfl_xor(s1, off, 64);
    s2 += __shfl_xor(s2, off, 64);
  }
  if (cg == 0) {
    const int row = rowbase + r;
    float c0 = s1 + SHIFT;
    float c = fmaxf(c0, SLOPE * c0);
    Etab[(size_t)row * 2]     = __expf(s1 - c);
    Etab[(size_t)row * 2 + 1] = __expf(SLOPE * s1 - c);
    FbfF[row]  = f2bf(__expf(s2));
    FbfF2[row] = f2bf(__expf(SLOPE * s2));
  }
  __syncthreads();

  if (tid < 128) {
    u32x4 v = *(const u32x4*)&tile[tid][0];
    *(u32x4*)(ht + (size_t)tid * NN + rowbase) = v;
  }
}

// ---------------------------------------------------------------------------
// Kernel B: fused masked-softmax aggregation, v14.
// v13 post-mortem (k_gat ~100 us inferred vs ~30 modeled; the 64-line-scatter
// fix bought only ~11 us): the unmodeled dominant term is the epilogue's
// 8.4M device-scope fp32 atomicAdds (v12 grew them 16x over v10). On MI355X
// per-XCD L2s are non-coherent, so device atomics to the shared out region
// serialize at the memory-side coherence point (~60-110 us at plausible
// fabric-atomic rates). v14:
//  * ATOMIC-FREE finish: block stores its 128x128 partial tile with plain
//    coalesced stores into part[CB][8192][128] via an LDS bounce (reuse dead
//    sH as 128x64 fp32 staging, 2 halves); den partials to denp[CB][8192].
//    k_fin reduces 8 partials (+den +bias): 44 MB streamed, ~8 us.
//  * adjp2 PRELOADED whole (16 KB contiguous per block, 2 cp16 per wave,
//    once): removes the HBM-cold stream from every per-chunk vmcnt drain.
//    Per-chunk DMA is now only L2-resident ht + sF.
//  * LDS 32+16+0.5 = 48.5 KB -> 2-3 blocks/CU.
// ---------------------------------------------------------------------------
__global__ __launch_bounds__(512, 4) void k_gat(const unsigned int* __restrict__ adjp2,
                                                const unsigned short* __restrict__ ht,
                                                const float* __restrict__ Etab,
                                                const unsigned short* __restrict__ FbfF,
                                                const unsigned short* __restrict__ FbfF2,
                                                float* __restrict__ part,
                                                float* __restrict__ denp) {
  __shared__ unsigned short sH[2][128 * 64]; // 32 KB : ht, slot s holds group s^(f&7)
  __shared__ unsigned int sAp[16][2][128];   // 16 KB : ALL 16 chunks, preloaded once
  __shared__ unsigned short sF[2][128];      // 512 B : [0,64)=F plane, [64,128)=F2

  const int tid = threadIdx.x;
  const int wave = tid >> 6;                 // 0..7, owns rows 16w..16w+15
  const int lane = tid & 63;
  const int quad = lane >> 4;
  const int m = lane & 15;                   // A-row label within wave's 16
  const int rowbase = (int)(blockIdx.x >> 3) * 128;
  const int colbase = (int)(blockIdx.x & 7) * 1024;
  const int CB = (int)(blockIdx.x & 7);
  const int row = rowbase + wave * 16 + m;

  // ---- runtime layout probes (exact in bf16/fp32) ----
  bf16x8 pm, pinv, pones;
  #pragma unroll
  for (int jj = 0; jj < 8; ++jj) {
    pm[jj] = (__bf16)(float)m;
    pinv[jj] = (__bf16)0.03125f;
    pones[jj] = (__bf16)1.0f;
  }
  f32x4 z = {0.f, 0.f, 0.f, 0.f};
  f32x4 rp = __builtin_amdgcn_mfma_f32_16x16x32_bf16(pm, pinv, z, 0, 0, 0);
  f32x4 cp = __builtin_amdgcn_mfma_f32_16x16x32_bf16(pinv, pm, z, 0, 0, 0);
  int rowmap[4], colmap[4];
  #pragma unroll
  for (int r = 0; r < 4; ++r) {
    rowmap[r] = ((int)(rp[r] + 0.5f)) & 15;
    colmap[r] = ((int)(cp[r] + 0.5f)) & 15;
  }

  const float E  = Etab[(size_t)row * 2];
  const float E2 = Etab[(size_t)row * 2 + 1];

  f32x4 acc[8];
  #pragma unroll
  for (int t = 0; t < 8; ++t) acc[t] = z;
  f32x4 den = z;

  // ---- DMA source pointers ----
  const unsigned short* srcH[2];
  #pragma unroll
  for (int il = 0; il < 2; ++il) {
    const int i = wave * 2 + il;
    const int f = i * 8 + (lane >> 3);
    const int g = (lane & 7) ^ (lane >> 3);
    srcH[il] = ht + (size_t)f * NN + colbase + g * 8;
  }
  const unsigned short* srcF = nullptr;
  if (wave == 1) {
    srcF = (lane < 8) ? (FbfF + colbase + lane * 8)
                      : (FbfF2 + colbase + (lane - 8) * 8);
  }

  auto stage = [&](int b, int c) {
    #pragma unroll
    for (int il = 0; il < 2; ++il)
      async_cp16(&sH[b][(wave * 2 + il) * 512], srcH[il] + c * 64);
    if (wave == 1 && lane < 16) async_cp16(&sF[b][0], srcF + c * 64);
  };

  auto compute = [&](int cs, int c) {
    #pragma unroll
    for (int k32 = 0; k32 < 2; ++k32) {
      const unsigned int word = sAp[c][k32][wave * 16 + m];
      const unsigned int byt = (word >> (quad * 8)) & 0xffu;
      const int jl = k32 * 32 + quad * 8;
      u32x4 Fq = *(const u32x4*)&sF[cs][jl];        // 8 bf16 F
      u32x4 Gq = *(const u32x4*)&sF[cs][64 + jl];   // 8 bf16 F2

      bf16x8 af;
      #pragma unroll
      for (int p = 0; p < 4; ++p) {
        const unsigned fp = Fq[p], gp = Gq[p];
        const float Flo = __builtin_bit_cast(float, fp << 16);
        const float Fhi = __builtin_bit_cast(float, fp & 0xffff0000u);
        const float Glo = __builtin_bit_cast(float, gp << 16);
        const float Ghi = __builtin_bit_cast(float, gp & 0xffff0000u);
        const float wlo = fmaxf(E * Flo, E2 * Glo);
        const float whi = fmaxf(E * Fhi, E2 * Ghi);
        af[p * 2]     = (byt & (1u << (p * 2)))     ? (__bf16)wlo : (__bf16)0.0f;
        af[p * 2 + 1] = (byt & (1u << (p * 2 + 1))) ? (__bf16)whi : (__bf16)0.0f;
      }

      // ht frags: tile t, slot s = (4k32+quad) ^ (m&7); same af for all 8 t
      const int s0 = (k32 * 4 + quad) ^ (m & 7);
      #pragma unroll
      for (int t = 0; t < 8; ++t) {
        bf16x8 bt = __builtin_bit_cast(bf16x8,
            *(const u32x4*)&sH[cs][(t * 16 + m) * 64 + s0 * 8]);
        acc[t] = __builtin_amdgcn_mfma_f32_16x16x32_bf16(af, bt, acc[t], 0, 0, 0);
      }
      den = __builtin_amdgcn_mfma_f32_16x16x32_bf16(af, pones, den, 0, 0, 0);
    }
  };

  // ---- prologue: preload ALL adjp2 (16 KB contiguous) + chunk 0 ----
  {
    const unsigned int* srcAp = adjp2 + (size_t)blockIdx.x * 4096;
    #pragma unroll
    for (int il = 0; il < 2; ++il)
      async_cp16(((unsigned int*)sAp) + (wave * 2 + il) * 256,
                 srcAp + (wave * 2 + il) * 256 + lane * 4);
  }
  stage(0, 0);   // chunk 0 -> buffer 0

  // 16 chunks of 64 cols over this block's 1024-col eighth; v10 protocol:
  // barrier drains chunk c's DMA (issued one compute phase ago), then prefetch.
  #pragma unroll 1
  for (int c = 0; c < 16; c += 2) {
    __syncthreads();                 // drains chunk c DMA (+adjp preload @c=0)
    stage(1, c + 1);                 // prefetch c+1: in flight across compute
    compute(0, c);                   // chunk c (buffer 0)
    __syncthreads();                 // drains chunk c+1; fences buf0 readers
    if (c + 2 < 16) stage(0, c + 2); // prefetch c+2
    compute(1, c + 1);               // chunk c+1 (buffer 1)
  }

  // ---- epilogue: coalesced partial stores via LDS bounce (NO atomics) ----
  float* sOut = (float*)&sH[0][0];   // 32 KB = 128 rows x 64 cols fp32
  #pragma unroll
  for (int h = 0; h < 2; ++h) {
    __syncthreads();                 // sH readers done / previous half stored
    #pragma unroll
    for (int r = 0; r < 4; ++r) {
      #pragma unroll
      for (int tt = 0; tt < 4; ++tt) {
        sOut[(wave * 16 + rowmap[r]) * 64 + tt * 16 + colmap[r]] =
            acc[h * 4 + tt][r];
      }
    }
    __syncthreads();
    #pragma unroll
    for (int i = 0; i < 4; ++i) {
      const int v = i * 512 + tid;          // f32x4 index, 2048 total
      const int rl = v >> 4, c4 = v & 15;   // 16 f32x4 per 64-col row
      *(f32x4*)&part[((size_t)CB * NN + rowbase + rl) * FOUT + h * 64 + c4 * 4] =
          ((const f32x4*)sOut)[v];
    }
  }
  // den partials: plain stores, lanes m==0 cover rows quad*4+r (16/wave)
  if (m == 0) {
    #pragma unroll
    for (int r = 0; r < 4; ++r)
      denp[(size_t)CB * NN + rowbase + wave * 16 + rowmap[r]] = den[r];
  }
}

// ---------------------------------------------------------------------------
// k_fin: out = (sum_cb part) / (sum_cb denp) + bias
// ---------------------------------------------------------------------------
__global__ __launch_bounds__(256) void k_fin(const float* __restrict__ part,
                                             const float* __restrict__ denp,
                                             const float* __restrict__ bias,
                                             float* __restrict__ out) {
  const int i4 = blockIdx.x * 256 + threadIdx.x;  // f32x4 index over out
  const int rowi = i4 >> 5;                       // 32 f32x4 per row
  const int f = (i4 & 31) * 4;
  float den = 0.f;
  f32x4 s = {0.f, 0.f, 0.f, 0.f};
  #pragma unroll
  for (int cb = 0; cb < 8; ++cb) {
    den += denp[(size_t)cb * NN + rowi];
    f32x4 p = *(const f32x4*)&part[((size_t)cb * NN + rowi) * FOUT + f];
    s[0] += p[0]; s[1] += p[1]; s[2] += p[2]; s[3] += p[3];
  }
  const float inv = 1.0f / den;
  f32x4 b = *(const f32x4*)(bias + f);
  f32x4 v = {s[0] * inv + b[0], s[1] * inv + b[1],
             s[2] * inv + b[2], s[3] * inv + b[3]};
  *(f32x4*)(out + (size_t)rowi * FOUT + f) = v;
}

// ---------------------------------------------------------------------------
extern "C" void kernel_launch(void* const* d_in, const int* in_sizes, int n_in,
                              void* d_out, int out_size, void* d_ws, size_t ws_size,
                              hipStream_t stream) {
  const float* x    = (const float*)d_in[0];
  const int*   adj  = (const int*)d_in[1];
  const float* W    = (const float*)d_in[2];
  const float* a1   = (const float*)d_in[3];
  const float* a2   = (const float*)d_in[4];
  const float* bias = (const float*)d_in[5];
  float* out = (float*)d_out;

  char* ws = (char*)d_ws;
  unsigned short* ht = (unsigned short*)ws;                            // 2 MB
  float* Etab = (float*)(ws + (size_t)2 * 1024 * 1024);                // 64 KB
  unsigned short* FbfF =
      (unsigned short*)(ws + (size_t)2 * 1024 * 1024 + 64 * 1024);     // 16 KB
  unsigned short* FbfF2 = FbfF + NN;                                   // 16 KB
  unsigned int* adjp2 =
      (unsigned int*)(ws + (size_t)2 * 1024 * 1024 + 128 * 1024);      // 8 MB
  float* part = (float*)(ws + (size_t)12 * 1024 * 1024);               // 32 MB
  float* denp = (float*)(ws + (size_t)44 * 1024 * 1024);               // 256 KB

  k_pack<<<2048, 256, 0, stream>>>(adj, adjp2);
  k_hw<<<NN / 8, 256, 0, stream>>>(x, W, a1, a2, ht, Etab, FbfF, FbfF2);
  k_gat<<<512, 512, 0, stream>>>(adjp2, ht, Etab, FbfF, FbfF2, part, denp);
  k_fin<<<(NN * FOUT / 4) / 256, 256, 0, stream>>>(part, denp, bias, out);
}